// Round 9
// baseline (53.827 us; speedup 1.0000x reference)
//
#include <hip/hip_runtime.h>
#include <math.h>

// Balloon-Windkessel BOLD, 1000-step Euler. R9:
//  R8 residual (~7.5us kernel) decomposed: per-pass skeleton cost -- 3 serial
//  ds_bpermute shuffles (predw, eP, eQ), 2 barriers, SCX LDS round-trip --
//  dominated over the DPP scan stages. R9 collapses the skeleton:
//   - predw/SCX eliminated: next-pass vb[0] (traj at 4tid-1) IS this pass's
//     composed-prefix x, already in a register. Kills 1 shuffle + 1 barrier.
//   - ping-pong SCv[2][4] replaces the write/read race barrier.
//   - exclusive shift via DPP wave_shr1 (0x138) -- no ds_bpermute left.
//   - 4 passes (lin@1, Newton, Newton, fused Newton+q-scan): traj at fused
//     pass has e~1.6e-5 -> q linearization error ~2e-5, y err ~3e-6.

namespace {
constexpr int   kChunks = 250;               // 4 steps per thread
constexpr float kDt     = 0.01f;
constexpr float kInvRho = 1.0f / 0.34f;
constexpr float kV0 = 0.02f, kK1 = 2.38f, kK2 = 2.0f, kK3 = 0.48f;
// discrete-eigen closed form for f_t (R4-validated):
constexpr float kLog2R    = -0.0071769251f;   // log2(|lambda|)
constexpr float kThetaRev =  0.0013852133f;   // arg(lambda)/(2pi), v_sin units
constexpr float kCB       = -0.57735026919f;  // -1/sqrt(3)
constexpr float kL2OneMR  = -0.5994620704f;   // log2(0.66)
constexpr float kPwm1     = 2.125f;           // 3.125 - 1
}

template<int Ctrl, int RowMask>
__device__ __forceinline__ float dppf(float x, float ident) {
    return __int_as_float(__builtin_amdgcn_update_dpp(
        __float_as_int(ident), __float_as_int(x), Ctrl, RowMask, 0xF, false));
}

// inclusive wave64 scan of linear-map composites (P,Q): x <- x o y (y earlier)
__device__ __forceinline__ void wave_scan2(float& xP, float& xQ) {
    #define ST(C, M) { float yP = dppf<C, M>(xP, 1.0f);            \
                       float yQ = dppf<C, M>(xQ, 0.0f);            \
                       xQ = fmaf(xP, yQ, xQ); xP *= yP; }
    ST(0x111, 0xF) ST(0x112, 0xF) ST(0x114, 0xF) ST(0x118, 0xF)
    ST(0x142, 0xA) ST(0x143, 0xC)
    #undef ST
}
__device__ __forceinline__ void wave_scan4(float& xP, float& xQ,
                                           float& uP, float& uQ) {
    #define ST(C, M) { float yP = dppf<C, M>(xP, 1.0f);            \
                       float yQ = dppf<C, M>(xQ, 0.0f);            \
                       float zP = dppf<C, M>(uP, 1.0f);            \
                       float zQ = dppf<C, M>(uQ, 0.0f);            \
                       xQ = fmaf(xP, yQ, xQ); xP *= yP;            \
                       uQ = fmaf(uP, zQ, uQ); uP *= zP; }
    ST(0x111, 0xF) ST(0x112, 0xF) ST(0x114, 0xF) ST(0x118, 0xF)
    ST(0x142, 0xA) ST(0x143, 0xC)
    #undef ST
}

__global__ __launch_bounds__(256)
void bold_kernel(const void* __restrict__ mtt_raw, float* __restrict__ out) {
    __shared__ float2 SCv[2][4];  // ping-pong per-wave v-composite aggregates
    __shared__ float2 SCq[4];     // per-wave q-composite aggregates (last pass)
    const int tid  = threadIdx.x;
    const int lane = tid & 63, wid = tid >> 6;

    unsigned bits = *(const unsigned*)mtt_raw;
    float mtt = ((bits & 0xFFFFu) == 0u) ? __uint_as_float(bits)
                                         : __uint_as_float(bits << 16);
    const float c1  = kDt / mtt;
    const float c31 = 3.125f * c1;
    const float c21 = kPwm1 * c1;

    // ---- Prologue: Fc[k] = c1*f_t (closed-form f), Bq[k] = c1*f*E/rho ----
    float Fc[4] = {0, 0, 0, 0}, Bq[4] = {0, 0, 0, 0};
    if (tid < kChunks) {
        #pragma unroll
        for (int k = 0; k < 4; ++k) {
            float tf = (float)(4 * tid + k);
            float rt = __builtin_amdgcn_exp2f(tf * kLog2R);
            float ar = tf * kThetaRev;
            float sn = __builtin_amdgcn_sinf(ar);
            float cs = __builtin_amdgcn_cosf(ar);
            float ft = fmaf(rt, fmaf(kCB, sn, -cs), 2.0f);      // exact f_t
            float E1 = __builtin_amdgcn_exp2f(kL2OneMR * __builtin_amdgcn_rcpf(ft));
            Fc[k] = c1 * ft;
            Bq[k] = (c1 * kInvRho) * ft * (1.0f - E1);
        }
    }

    float4 X = make_float4(1.f, 1.f, 1.f, 1.f);   // trajectory chunk (regs)
    float xprev = 1.0f;                           // trajectory at 4tid-1
    float A[4] = {1, 1, 1, 1}, B[4] = {0, 0, 0, 0};

    // ---- Pass 0: linearize at v==1 -> closed-form A,B, no transcendentals --
    {
        float Pc = 1.0f, Qc = 0.0f;
        const float A0 = 1.0f - c31;
        if (tid < kChunks) {
            #pragma unroll
            for (int k = 0; k < 4; ++k) {
                A[k] = A0; B[k] = Fc[k] + c21;
                Qc = fmaf(A0, Qc, B[k]); Pc *= A0;
            }
        }
        float xP = Pc, xQ = Qc;
        wave_scan2(xP, xQ);
        if (lane == 63) SCv[0][wid] = make_float2(xP, xQ);
        __syncthreads();
        float eP = dppf<0x138, 0xF>(xP, 1.0f);    // wave_shr1, lane0 -> ident
        float eQ = dppf<0x138, 0xF>(xQ, 0.0f);
        float2 a0 = SCv[0][0], a1 = SCv[0][1], a2 = SCv[0][2];
        float wP = 1.f, wQ = 0.f;
        if (wid >= 1) { wP = a0.x; wQ = a0.y; }
        if (wid >= 2) { wQ = fmaf(a1.x, wQ, a1.y); wP *= a1.x; }
        if (wid >= 3) { wQ = fmaf(a2.x, wQ, a2.y); wP *= a2.x; }
        float x = fmaf(eP, wQ, eQ) + eP * wP;     // new traj at 4tid-1
        xprev = x;
        x = fmaf(A[0], x, B[0]); X.x = x;
        x = fmaf(A[1], x, B[1]); X.y = x;
        x = fmaf(A[2], x, B[2]); X.z = x;
        x = fmaf(A[3], x, B[3]); X.w = x;
    }

    // ---- Passes 1..2: full Newton; single barrier each, ping-pong SCv ----
    #pragma unroll
    for (int sw = 0; sw < 2; ++sw) {
        const int buf = 1 - sw;                   // pass1->buf1, pass2->buf0
        float Pc = 1.0f, Qc = 0.0f;
        if (tid < kChunks) {
            float vb[4] = {xprev, X.x, X.y, X.z};
            #pragma unroll
            for (int k = 0; k < 4; ++k) {
                float w  = __builtin_amdgcn_exp2f(
                               kPwm1 * __builtin_amdgcn_logf(vb[k])); // v^2.125
                float p3 = w * vb[k];                                 // v^3.125
                float At = fmaf(-c31, w, 1.0f);
                float Bt = fmaf(c21, p3, Fc[k]);
                A[k] = At; B[k] = Bt;
                Qc = fmaf(At, Qc, Bt); Pc = At * Pc;
            }
        }
        float xP = Pc, xQ = Qc;
        wave_scan2(xP, xQ);
        if (lane == 63) SCv[buf][wid] = make_float2(xP, xQ);
        __syncthreads();
        float eP = dppf<0x138, 0xF>(xP, 1.0f);
        float eQ = dppf<0x138, 0xF>(xQ, 0.0f);
        float2 a0 = SCv[buf][0], a1 = SCv[buf][1], a2 = SCv[buf][2];
        float wP = 1.f, wQ = 0.f;
        if (wid >= 1) { wP = a0.x; wQ = a0.y; }
        if (wid >= 2) { wQ = fmaf(a1.x, wQ, a1.y); wP *= a1.x; }
        if (wid >= 3) { wQ = fmaf(a2.x, wQ, a2.y); wP *= a2.x; }
        float x = fmaf(eP, wQ, eQ) + eP * wP;
        xprev = x;
        x = fmaf(A[0], x, B[0]); X.x = x;
        x = fmaf(A[1], x, B[1]); X.y = x;
        x = fmaf(A[2], x, B[2]); X.z = x;
        x = fmaf(A[3], x, B[3]); X.w = x;
    }

    // ---- Pass 3 (final): Newton sweep FUSED with q-scan + readout ----
    {
        float Pv = 1.f, Qv = 0.f, Pq = 1.f, Qq = 0.f;
        float Aq[4] = {1, 1, 1, 1};
        if (tid < kChunks) {
            float vb[4] = {xprev, X.x, X.y, X.z};
            #pragma unroll
            for (int k = 0; k < 4; ++k) {
                float w   = __builtin_amdgcn_exp2f(
                                kPwm1 * __builtin_amdgcn_logf(vb[k]));
                float p3  = w * vb[k];
                float At  = fmaf(-c31, w, 1.0f);
                float Bt  = fmaf(c21, p3, Fc[k]);
                float Aqt = fmaf(-c1, w, 1.0f);       // 1 - c1*v^2.125 (free w)
                A[k] = At; B[k] = Bt; Aq[k] = Aqt;
                Qv = fmaf(At, Qv, Bt);     Pv = At * Pv;
                Qq = fmaf(Aqt, Qq, Bq[k]); Pq = Aqt * Pq;
            }
        }
        float xP = Pv, xQ = Qv, uP = Pq, uQ = Qq;
        wave_scan4(xP, xQ, uP, uQ);
        if (lane == 63) { SCv[1][wid] = make_float2(xP, xQ);
                          SCq[wid]    = make_float2(uP, uQ); }
        __syncthreads();
        float eP = dppf<0x138, 0xF>(xP, 1.0f);
        float eQ = dppf<0x138, 0xF>(xQ, 0.0f);
        float fP = dppf<0x138, 0xF>(uP, 1.0f);
        float fQ = dppf<0x138, 0xF>(uQ, 0.0f);
        float2 a0 = SCv[1][0], a1 = SCv[1][1], a2 = SCv[1][2];
        float2 b0 = SCq[0],    b1 = SCq[1],    b2 = SCq[2];
        float wP = 1.f, wQ = 0.f, vP = 1.f, vQ = 0.f;
        if (wid >= 1) { wP = a0.x; wQ = a0.y; vP = b0.x; vQ = b0.y; }
        if (wid >= 2) { wQ = fmaf(a1.x, wQ, a1.y); wP *= a1.x;
                        vQ = fmaf(b1.x, vQ, b1.y); vP *= b1.x; }
        if (wid >= 3) { wQ = fmaf(a2.x, wQ, a2.y); wP *= a2.x;
                        vQ = fmaf(b2.x, vQ, b2.y); vP *= b2.x; }
        if (tid < kChunks) {
            float x = fmaf(eP, wQ, eQ) + eP * wP;     // v_{4tid}
            float q = fmaf(fP, vQ, fQ) + fP * vP;     // q_{4tid} (q_0 = 1)
            float yv[4];
            #pragma unroll
            for (int k = 0; k < 4; ++k) {
                x = fmaf(A[k],  x, B[k]);             // v_{t+1}
                q = fmaf(Aq[k], q, Bq[k]);            // q_{t+1}
                yv[k] = kV0 * (kK1 * (1.0f - q)
                             + kK2 * fmaf(-q, __builtin_amdgcn_rcpf(x), 1.0f)
                             + kK3 * (1.0f - x));
            }
            ((float4*)out)[tid] = make_float4(yv[0], yv[1], yv[2], yv[3]);
        }
    }
}

extern "C" void kernel_launch(void* const* d_in, const int* in_sizes, int n_in,
                              void* d_out, int out_size, void* d_ws, size_t ws_size,
                              hipStream_t stream) {
    bold_kernel<<<dim3(1), dim3(256), 0, stream>>>(d_in[0], (float*)d_out);
}

// Round 10
// 53.459 us; speedup vs baseline: 1.0069x; 1.0069x over previous
//
#include <hip/hip_runtime.h>
#include <math.h>

// Balloon-Windkessel BOLD, 1000-step Euler. R10:
//  R9 post-mortem: removing a pass + 4 barriers + all bpermutes was TIMING-
//  NEUTRAL (53.5 -> 53.8) -> per-pass marginal cost ~0.3us; measured "kernel"
//  time is ~5us fixed 1-block dispatch/drain + ~2us body. We sit on the
//  harness floor (39.5us ws re-poison fill + ~6us launch/sync). But R9's
//  dropped sweep cost 2000x accuracy (1.2e-7 -> 2.4e-4, margin 2.7x): Newton
//  contraction is slower than modeled. R10 = R9 slim skeleton + R8 pass count:
//  pass0 (lin@1) + 3 Newton sweeps + fused Newton/q-scan pass. Expected
//  neutral time, absmax back to ~1e-7.

namespace {
constexpr int   kChunks = 250;               // 4 steps per thread
constexpr float kDt     = 0.01f;
constexpr float kInvRho = 1.0f / 0.34f;
constexpr float kV0 = 0.02f, kK1 = 2.38f, kK2 = 2.0f, kK3 = 0.48f;
// discrete-eigen closed form for f_t (R4-validated):
constexpr float kLog2R    = -0.0071769251f;   // log2(|lambda|)
constexpr float kThetaRev =  0.0013852133f;   // arg(lambda)/(2pi), v_sin units
constexpr float kCB       = -0.57735026919f;  // -1/sqrt(3)
constexpr float kL2OneMR  = -0.5994620704f;   // log2(0.66)
constexpr float kPwm1     = 2.125f;           // 3.125 - 1
}

template<int Ctrl, int RowMask>
__device__ __forceinline__ float dppf(float x, float ident) {
    return __int_as_float(__builtin_amdgcn_update_dpp(
        __float_as_int(ident), __float_as_int(x), Ctrl, RowMask, 0xF, false));
}

// inclusive wave64 scan of linear-map composites (P,Q): x <- x o y (y earlier)
__device__ __forceinline__ void wave_scan2(float& xP, float& xQ) {
    #define ST(C, M) { float yP = dppf<C, M>(xP, 1.0f);            \
                       float yQ = dppf<C, M>(xQ, 0.0f);            \
                       xQ = fmaf(xP, yQ, xQ); xP *= yP; }
    ST(0x111, 0xF) ST(0x112, 0xF) ST(0x114, 0xF) ST(0x118, 0xF)
    ST(0x142, 0xA) ST(0x143, 0xC)
    #undef ST
}
__device__ __forceinline__ void wave_scan4(float& xP, float& xQ,
                                           float& uP, float& uQ) {
    #define ST(C, M) { float yP = dppf<C, M>(xP, 1.0f);            \
                       float yQ = dppf<C, M>(xQ, 0.0f);            \
                       float zP = dppf<C, M>(uP, 1.0f);            \
                       float zQ = dppf<C, M>(uQ, 0.0f);            \
                       xQ = fmaf(xP, yQ, xQ); xP *= yP;            \
                       uQ = fmaf(uP, zQ, uQ); uP *= zP; }
    ST(0x111, 0xF) ST(0x112, 0xF) ST(0x114, 0xF) ST(0x118, 0xF)
    ST(0x142, 0xA) ST(0x143, 0xC)
    #undef ST
}

__global__ __launch_bounds__(256)
void bold_kernel(const void* __restrict__ mtt_raw, float* __restrict__ out) {
    __shared__ float2 SCv[2][4];  // ping-pong per-wave v-composite aggregates
    __shared__ float2 SCq[4];     // per-wave q-composite aggregates (last pass)
    const int tid  = threadIdx.x;
    const int lane = tid & 63, wid = tid >> 6;

    unsigned bits = *(const unsigned*)mtt_raw;
    float mtt = ((bits & 0xFFFFu) == 0u) ? __uint_as_float(bits)
                                         : __uint_as_float(bits << 16);
    const float c1  = kDt / mtt;
    const float c31 = 3.125f * c1;
    const float c21 = kPwm1 * c1;

    // ---- Prologue: Fc[k] = c1*f_t (closed-form f), Bq[k] = c1*f*E/rho ----
    float Fc[4] = {0, 0, 0, 0}, Bq[4] = {0, 0, 0, 0};
    if (tid < kChunks) {
        #pragma unroll
        for (int k = 0; k < 4; ++k) {
            float tf = (float)(4 * tid + k);
            float rt = __builtin_amdgcn_exp2f(tf * kLog2R);
            float ar = tf * kThetaRev;
            float sn = __builtin_amdgcn_sinf(ar);
            float cs = __builtin_amdgcn_cosf(ar);
            float ft = fmaf(rt, fmaf(kCB, sn, -cs), 2.0f);      // exact f_t
            float E1 = __builtin_amdgcn_exp2f(kL2OneMR * __builtin_amdgcn_rcpf(ft));
            Fc[k] = c1 * ft;
            Bq[k] = (c1 * kInvRho) * ft * (1.0f - E1);
        }
    }

    float4 X = make_float4(1.f, 1.f, 1.f, 1.f);   // trajectory chunk (regs)
    float xprev = 1.0f;                           // trajectory at 4tid-1
    float A[4] = {1, 1, 1, 1}, B[4] = {0, 0, 0, 0};

    // ---- Pass 0: linearize at v==1 -> closed-form A,B, no transcendentals --
    {
        float Pc = 1.0f, Qc = 0.0f;
        const float A0 = 1.0f - c31;
        if (tid < kChunks) {
            #pragma unroll
            for (int k = 0; k < 4; ++k) {
                A[k] = A0; B[k] = Fc[k] + c21;
                Qc = fmaf(A0, Qc, B[k]); Pc *= A0;
            }
        }
        float xP = Pc, xQ = Qc;
        wave_scan2(xP, xQ);
        if (lane == 63) SCv[0][wid] = make_float2(xP, xQ);
        __syncthreads();
        float eP = dppf<0x138, 0xF>(xP, 1.0f);    // wave_shr1, lane0 -> ident
        float eQ = dppf<0x138, 0xF>(xQ, 0.0f);
        float2 a0 = SCv[0][0], a1 = SCv[0][1], a2 = SCv[0][2];
        float wP = 1.f, wQ = 0.f;
        if (wid >= 1) { wP = a0.x; wQ = a0.y; }
        if (wid >= 2) { wQ = fmaf(a1.x, wQ, a1.y); wP *= a1.x; }
        if (wid >= 3) { wQ = fmaf(a2.x, wQ, a2.y); wP *= a2.x; }
        float x = fmaf(eP, wQ, eQ) + eP * wP;     // new traj at 4tid-1
        xprev = x;
        x = fmaf(A[0], x, B[0]); X.x = x;
        x = fmaf(A[1], x, B[1]); X.y = x;
        x = fmaf(A[2], x, B[2]); X.z = x;
        x = fmaf(A[3], x, B[3]); X.w = x;
    }

    // ---- Passes 1..3: full Newton; single barrier each, ping-pong SCv ----
    #pragma unroll
    for (int sw = 0; sw < 3; ++sw) {
        const int buf = 1 - (sw & 1);             // pass1->1, pass2->0, pass3->1
        float Pc = 1.0f, Qc = 0.0f;
        if (tid < kChunks) {
            float vb[4] = {xprev, X.x, X.y, X.z};
            #pragma unroll
            for (int k = 0; k < 4; ++k) {
                float w  = __builtin_amdgcn_exp2f(
                               kPwm1 * __builtin_amdgcn_logf(vb[k])); // v^2.125
                float p3 = w * vb[k];                                 // v^3.125
                float At = fmaf(-c31, w, 1.0f);
                float Bt = fmaf(c21, p3, Fc[k]);
                A[k] = At; B[k] = Bt;
                Qc = fmaf(At, Qc, Bt); Pc = At * Pc;
            }
        }
        float xP = Pc, xQ = Qc;
        wave_scan2(xP, xQ);
        if (lane == 63) SCv[buf][wid] = make_float2(xP, xQ);
        __syncthreads();
        float eP = dppf<0x138, 0xF>(xP, 1.0f);
        float eQ = dppf<0x138, 0xF>(xQ, 0.0f);
        float2 a0 = SCv[buf][0], a1 = SCv[buf][1], a2 = SCv[buf][2];
        float wP = 1.f, wQ = 0.f;
        if (wid >= 1) { wP = a0.x; wQ = a0.y; }
        if (wid >= 2) { wQ = fmaf(a1.x, wQ, a1.y); wP *= a1.x; }
        if (wid >= 3) { wQ = fmaf(a2.x, wQ, a2.y); wP *= a2.x; }
        float x = fmaf(eP, wQ, eQ) + eP * wP;
        xprev = x;
        x = fmaf(A[0], x, B[0]); X.x = x;
        x = fmaf(A[1], x, B[1]); X.y = x;
        x = fmaf(A[2], x, B[2]); X.z = x;
        x = fmaf(A[3], x, B[3]); X.w = x;
    }

    // ---- Final pass: Newton sweep FUSED with q-scan + readout (buf 0) ----
    {
        float Pv = 1.f, Qv = 0.f, Pq = 1.f, Qq = 0.f;
        float Aq[4] = {1, 1, 1, 1};
        if (tid < kChunks) {
            float vb[4] = {xprev, X.x, X.y, X.z};
            #pragma unroll
            for (int k = 0; k < 4; ++k) {
                float w   = __builtin_amdgcn_exp2f(
                                kPwm1 * __builtin_amdgcn_logf(vb[k]));
                float p3  = w * vb[k];
                float At  = fmaf(-c31, w, 1.0f);
                float Bt  = fmaf(c21, p3, Fc[k]);
                float Aqt = fmaf(-c1, w, 1.0f);       // 1 - c1*v^2.125 (free w)
                A[k] = At; B[k] = Bt; Aq[k] = Aqt;
                Qv = fmaf(At, Qv, Bt);     Pv = At * Pv;
                Qq = fmaf(Aqt, Qq, Bq[k]); Pq = Aqt * Pq;
            }
        }
        float xP = Pv, xQ = Qv, uP = Pq, uQ = Qq;
        wave_scan4(xP, xQ, uP, uQ);
        if (lane == 63) { SCv[0][wid] = make_float2(xP, xQ);
                          SCq[wid]    = make_float2(uP, uQ); }
        __syncthreads();
        float eP = dppf<0x138, 0xF>(xP, 1.0f);
        float eQ = dppf<0x138, 0xF>(xQ, 0.0f);
        float fP = dppf<0x138, 0xF>(uP, 1.0f);
        float fQ = dppf<0x138, 0xF>(uQ, 0.0f);
        float2 a0 = SCv[0][0], a1 = SCv[0][1], a2 = SCv[0][2];
        float2 b0 = SCq[0],    b1 = SCq[1],    b2 = SCq[2];
        float wP = 1.f, wQ = 0.f, vP = 1.f, vQ = 0.f;
        if (wid >= 1) { wP = a0.x; wQ = a0.y; vP = b0.x; vQ = b0.y; }
        if (wid >= 2) { wQ = fmaf(a1.x, wQ, a1.y); wP *= a1.x;
                        vQ = fmaf(b1.x, vQ, b1.y); vP *= b1.x; }
        if (wid >= 3) { wQ = fmaf(a2.x, wQ, a2.y); wP *= a2.x;
                        vQ = fmaf(b2.x, vQ, b2.y); vP *= b2.x; }
        if (tid < kChunks) {
            float x = fmaf(eP, wQ, eQ) + eP * wP;     // v_{4tid}
            float q = fmaf(fP, vQ, fQ) + fP * vP;     // q_{4tid} (q_0 = 1)
            float yv[4];
            #pragma unroll
            for (int k = 0; k < 4; ++k) {
                x = fmaf(A[k],  x, B[k]);             // v_{t+1}
                q = fmaf(Aq[k], q, Bq[k]);            // q_{t+1}
                yv[k] = kV0 * (kK1 * (1.0f - q)
                             + kK2 * fmaf(-q, __builtin_amdgcn_rcpf(x), 1.0f)
                             + kK3 * (1.0f - x));
            }
            ((float4*)out)[tid] = make_float4(yv[0], yv[1], yv[2], yv[3]);
        }
    }
}

extern "C" void kernel_launch(void* const* d_in, const int* in_sizes, int n_in,
                              void* d_out, int out_size, void* d_ws, size_t ws_size,
                              hipStream_t stream) {
    bold_kernel<<<dim3(1), dim3(256), 0, stream>>>(d_in[0], (float*)d_out);
}